// Round 7
// baseline (241.783 us; speedup 1.0000x reference)
//
#include <hip/hip_runtime.h>
#include <math.h>

// Problem constants: U=4 users, NT=8 antennas, BATCH*CWH = 6,291,456 fp32 per plane.
#define UU 4
#define NTT 8
#define BC4 1572864            // (BATCH*CWH)/4 float4 groups per plane
#define THREADS 256
#define NBLOCKS (BC4 / THREADS)   // 6144 blocks, TILE=1, exact cover

typedef float f32x4 __attribute__((ext_vector_type(4)));

// Single fused kernel.
//
// Ladder so far (dispatch time):
//   R1  nt loads + nt stores, TILE=4:        61.3 us, 3.29 TB/s fabric
//   R4  cached loads + nt stores, TILE=4:   102.4 us  (cached loads 1.67x WORSE,
//       FETCH_SIZE identical -> nt loads bypass L1/L2 allocation, faster path)
//   R5  nt loads + nt stores, TILE=1, 6144 blocks: 59.7-61.7 us; occupancy
//       31->42% but duration flat -> THROUGHPUT-capped at ~5.0 TB/s logical
//       (302 MB / 60 us) vs 6.29 TB/s m13 copy ceiling.
//
// Round-6 single-variable change (rerun; infra failure): stores nt -> PLAIN.
// nt stores drain all 98 MB of output to DRAM inside the dispatch window,
// competing with read fetches. Plain stores let the memory-side LLC absorb
// the write burst with deferred write-back (the harness fill kernel with
// plain stores hits 6.5 TB/s). Loads stay nontemporal (R4 proved that
// direction).
//
// Math (matches reference):
//   out[u] = (sum_v c[u][v] * x[v]) + nc[u] * noise[u]
//   c[u][v] = sqrtP[v] * (sum_n H[n,u] W[n,v]) / amp[u]
//   nc[u]   = stddev[u] / amp[u],  amp[u] = sqrtP[u] * sum_n H[n,u] W[n,u]
__global__ __launch_bounds__(THREADS) void mix_kernel(
    const f32x4* __restrict__ x4,   // [U][BC4]
    const f32x4* __restrict__ n4,   // [U][BC4]
    const float* __restrict__ W,    // [NT][U]
    const float* __restrict__ H,    // [NT][U]
    const float* __restrict__ P,    // [U]
    const float* __restrict__ stddev, // [U]
    f32x4* __restrict__ o4)         // [U][BC4]
{
    // ---- per-thread coefficient computation (uniform addresses -> SGPRs) ----
    float c[UU][UU], nc[UU];
    {
        float sqrtP[UU];
#pragma unroll
        for (int v = 0; v < UU; ++v) sqrtP[v] = sqrtf(P[v]);
#pragma unroll
        for (int u = 0; u < UU; ++u) {
            float hw = 0.0f;
#pragma unroll
            for (int n = 0; n < NTT; ++n) hw += H[n * UU + u] * W[n * UU + u];
            const float inv_amp = 1.0f / (sqrtP[u] * hw);
#pragma unroll
            for (int v = 0; v < UU; ++v) {
                float m = 0.0f;
#pragma unroll
                for (int n = 0; n < NTT; ++n) m += H[n * UU + u] * W[n * UU + v];
                c[u][v] = m * sqrtP[v] * inv_amp;
            }
            nc[u] = stddev[u] * inv_amp;
        }
    }

    // ---- memory-bound mixing: one float4 per plane per thread ----
    const int i4 = blockIdx.x * THREADS + threadIdx.x;

    // Issue ALL 8 loads before any compute/store: max loads in flight.
    f32x4 xv[UU], nv[UU];
#pragma unroll
    for (int v = 0; v < UU; ++v)
        xv[v] = __builtin_nontemporal_load(&x4[v * BC4 + i4]);
#pragma unroll
    for (int u = 0; u < UU; ++u)
        nv[u] = __builtin_nontemporal_load(&n4[u * BC4 + i4]);

    f32x4 acc[UU];
#pragma unroll
    for (int u = 0; u < UU; ++u) {
        acc[u] = nc[u] * nv[u];
#pragma unroll
        for (int v = 0; v < UU; ++v)
            acc[u] += c[u][v] * xv[v];
    }

    // PLAIN stores: let LLC absorb the write burst, write-back deferred.
#pragma unroll
    for (int u = 0; u < UU; ++u)
        o4[u * BC4 + i4] = acc[u];
}

extern "C" void kernel_launch(void* const* d_in, const int* in_sizes, int n_in,
                              void* d_out, int out_size, void* d_ws, size_t ws_size,
                              hipStream_t stream) {
    const float* x      = (const float*)d_in[0];
    const float* W      = (const float*)d_in[1];
    const float* H      = (const float*)d_in[2];
    const float* P      = (const float*)d_in[3];
    const float* stddev = (const float*)d_in[4];
    const float* noise  = (const float*)d_in[5];
    float* out = (float*)d_out;

    mix_kernel<<<NBLOCKS, THREADS, 0, stream>>>(
        (const f32x4*)x, (const f32x4*)noise, W, H, P, stddev, (f32x4*)out);
}

// Round 8
// 236.466 us; speedup vs baseline: 1.0225x; 1.0225x over previous
//
#include <hip/hip_runtime.h>
#include <math.h>

// Problem constants: U=4 users, NT=8 antennas, BATCH*CWH = 6,291,456 fp32 per plane.
#define UU 4
#define NTT 8
#define BC4 1572864            // (BATCH*CWH)/4 float4 groups per plane
#define THREADS 256
#define TILE 4                 // float4 positions per thread, plane-major bursts
#define NBLOCKS (BC4 / (THREADS * TILE))   // 1536 blocks, exact cover

typedef float f32x4 __attribute__((ext_vector_type(4)));

// Ladder (dispatch time, all passed):
//   R1  nt/nt, TILE=4, plane-inner interleave:   61.3 us, 5.0 TB/s logical
//   R4  cached loads + nt stores:               102.4 us  (cached loads 1.67x worse)
//   R5  nt/nt, TILE=1, 6144 blocks:              60   us  (4x waves -> flat:
//       THROUGHPUT-capped, not latency/occupancy)
//   R7  nt loads + PLAIN stores:                 64.5 us  (WRITE_SIZE unchanged:
//       LLC does not defer the write burst; plain store path slower)
//
// Round-8 change: burst-per-stream scheduling. The wave touches 12 streams
// whose addresses are congruent mod 24 MB (plane stride), so fine-grain
// plane-interleaved issue puts ~12 distinct DRAM rows + write turnarounds on
// the same channel concurrently. Restructure: PHASE 1 issues all reads
// plane-major (4 KB contiguous burst per stream: 4 x 1 KB wave-requests
// back-to-back), PHASE 2 computes, PHASE 3 issues all writes plane-major.
// Fewer row switches and R/W turnarounds per byte. nt on both (proven best).
//
// Math (matches reference):
//   out[u] = (sum_v c[u][v] * x[v]) + nc[u] * noise[u]
//   c[u][v] = sqrtP[v] * (sum_n H[n,u] W[n,v]) / amp[u]
//   nc[u]   = stddev[u] / amp[u],  amp[u] = sqrtP[u] * sum_n H[n,u] W[n,u]
__global__ __launch_bounds__(THREADS) void mix_kernel(
    const f32x4* __restrict__ x4,   // [U][BC4]
    const f32x4* __restrict__ n4,   // [U][BC4]
    const float* __restrict__ W,    // [NT][U]
    const float* __restrict__ H,    // [NT][U]
    const float* __restrict__ P,    // [U]
    const float* __restrict__ stddev, // [U]
    f32x4* __restrict__ o4)         // [U][BC4]
{
    // ---- per-thread coefficient computation (uniform addresses) ----
    float c[UU][UU], nc[UU];
    {
        float sqrtP[UU];
#pragma unroll
        for (int v = 0; v < UU; ++v) sqrtP[v] = sqrtf(P[v]);
#pragma unroll
        for (int u = 0; u < UU; ++u) {
            float hw = 0.0f;
#pragma unroll
            for (int n = 0; n < NTT; ++n) hw += H[n * UU + u] * W[n * UU + u];
            const float inv_amp = 1.0f / (sqrtP[u] * hw);
#pragma unroll
            for (int v = 0; v < UU; ++v) {
                float m = 0.0f;
#pragma unroll
                for (int n = 0; n < NTT; ++n) m += H[n * UU + u] * W[n * UU + v];
                c[u][v] = m * sqrtP[v] * inv_amp;
            }
            nc[u] = stddev[u] * inv_amp;
        }
    }

    const int base = blockIdx.x * (THREADS * TILE) + threadIdx.x;

    // ---- PHASE 1: all reads, plane-major (4 KB burst per stream) ----
    f32x4 xv[UU][TILE];
#pragma unroll
    for (int v = 0; v < UU; ++v)
#pragma unroll
        for (int j = 0; j < TILE; ++j)
            xv[v][j] = __builtin_nontemporal_load(&x4[v * BC4 + base + j * THREADS]);

    f32x4 nv[UU][TILE];
#pragma unroll
    for (int u = 0; u < UU; ++u)
#pragma unroll
        for (int j = 0; j < TILE; ++j)
            nv[u][j] = __builtin_nontemporal_load(&n4[u * BC4 + base + j * THREADS]);

    // ---- PHASE 2: compute (overwrite nv in place as accumulator) ----
#pragma unroll
    for (int u = 0; u < UU; ++u)
#pragma unroll
        for (int j = 0; j < TILE; ++j) {
            f32x4 acc = nc[u] * nv[u][j];
#pragma unroll
            for (int v = 0; v < UU; ++v)
                acc += c[u][v] * xv[v][j];
            nv[u][j] = acc;
        }

    // ---- PHASE 3: all writes, plane-major (4 KB burst per stream) ----
#pragma unroll
    for (int u = 0; u < UU; ++u)
#pragma unroll
        for (int j = 0; j < TILE; ++j)
            __builtin_nontemporal_store(nv[u][j], &o4[u * BC4 + base + j * THREADS]);
}

extern "C" void kernel_launch(void* const* d_in, const int* in_sizes, int n_in,
                              void* d_out, int out_size, void* d_ws, size_t ws_size,
                              hipStream_t stream) {
    const float* x      = (const float*)d_in[0];
    const float* W      = (const float*)d_in[1];
    const float* H      = (const float*)d_in[2];
    const float* P      = (const float*)d_in[3];
    const float* stddev = (const float*)d_in[4];
    const float* noise  = (const float*)d_in[5];
    float* out = (float*)d_out;

    mix_kernel<<<NBLOCKS, THREADS, 0, stream>>>(
        (const f32x4*)x, (const f32x4*)noise, W, H, P, stddev, (f32x4*)out);
}